// Round 6
// baseline (2585.308 us; speedup 1.0000x reference)
//
#include <hip/hip_runtime.h>
#include <hip/hip_bf16.h>

typedef __bf16 bf16x8 __attribute__((ext_vector_type(8)));
typedef __bf16 bf16x4 __attribute__((ext_vector_type(4)));
typedef float  f32x4  __attribute__((ext_vector_type(4)));

#define S_LEN  256
#define BATCH  16
#define EDIM   512
#define HDIM   512
#define VOCAB  32000
#define G4     2048          // 4*H
#define M_ROWS 4096          // S*B
#define NWG_LSTM 32

// ------- ws layout (bytes) -------
#define OFF_CNTA  0                         // int counter, phase A (batches 0-7)
#define OFF_CNTB  128                       // int counter, phase B (batches 8-15)
#define OFF_BIAS  4096                      // float[2048] = b_ih + b_hh
#define OFF_X     12288                     // bf16[4096*512] gathered embeddings
#define OFF_WIH   (OFF_X + 4194304)         // bf16[2048*512]
#define OFF_WLIN  (OFF_WIH + 2097152)       // bf16[32000*512]
#define OFF_XP    (OFF_WLIN + 32768000)     // float[4096*2048]
#define OFF_HS    (OFF_XP + 33554432)       // bf16[257*16*512]; slab 0 zeroed (h_0)
// total = 76,836,864 bytes

// ---- device-coherent (write-through to Infinity Cache) ops ----
__device__ __forceinline__ void store_short_sc(__bf16* p, __bf16 v) {
  unsigned short u = __builtin_bit_cast(unsigned short, v);
  asm volatile("global_store_short %0, %1, off sc0 sc1" :: "v"(p), "v"(u) : "memory");
}
__device__ __forceinline__ int load_cnt_sc(const int* p) {
  int r;
  asm volatile("global_load_dword %0, %1, off sc0 sc1\n\ts_waitcnt vmcnt(0)"
               : "=v"(r) : "v"(p) : "memory");
  return r;
}

#define GLOAD_LDS(gsrc, ldst)                                                  \
  __builtin_amdgcn_global_load_lds(                                            \
      (const __attribute__((address_space(1))) void*)(gsrc),                   \
      (__attribute__((address_space(3))) void*)(ldst), 16, 0, 0)

// ---------------- prep kernels ----------------
__global__ __launch_bounds__(256) void k_gather_cast_x(
    const int* __restrict__ tok, const float* __restrict__ embed, __bf16* __restrict__ xb) {
  int i = blockIdx.x * blockDim.x + threadIdx.x;          // over 4096*128 float4 chunks
  const int total = M_ROWS * (EDIM / 4);
  for (; i < total; i += gridDim.x * blockDim.x) {
    int m = i >> 7, c = i & 127;
    int t = tok[m];
    float4 v = ((const float4*)(embed + (size_t)t * EDIM))[c];
    bf16x4 o = { (__bf16)v.x, (__bf16)v.y, (__bf16)v.z, (__bf16)v.w };
    ((bf16x4*)(xb + (size_t)m * EDIM))[c] = o;
  }
}

__global__ __launch_bounds__(256) void k_cast(
    const float* __restrict__ src, __bf16* __restrict__ dst, int n4) {
  int i = blockIdx.x * blockDim.x + threadIdx.x;
  for (; i < n4; i += gridDim.x * blockDim.x) {
    float4 v = ((const float4*)src)[i];
    bf16x4 o = { (__bf16)v.x, (__bf16)v.y, (__bf16)v.z, (__bf16)v.w };
    ((bf16x4*)dst)[i] = o;
  }
}

__global__ __launch_bounds__(256) void k_bias(
    const float* __restrict__ b_ih, const float* __restrict__ b_hh, float* __restrict__ bb) {
  int i = blockIdx.x * blockDim.x + threadIdx.x;
  if (i < G4) bb[i] = b_ih[i] + b_hh[i];
}

// ------- 128x128 MFMA GEMM (m97 structure): D[M,N] = A[M,K]*B[N,K]^T + bias[N] -------
__global__ __launch_bounds__(256) void k_gemm2(
    const __bf16* __restrict__ A, const __bf16* __restrict__ B,
    float* __restrict__ D, const float* __restrict__ bias,
    int M, int N, int K) {
  __shared__ __align__(16) __bf16 As[128 * 64];
  __shared__ __align__(16) __bf16 Bs[128 * 64];
  const int tid  = threadIdx.x;
  const int m0   = blockIdx.y * 128, n0 = blockIdx.x * 128;
  const int wave = tid >> 6, lane = tid & 63;
  const int wm   = (wave >> 1) * 64, wn = (wave & 1) * 64;
  const int lrow = lane & 15;
  const int kbyte = (lane >> 4) * 16;           // byte offset within 128B LDS row
  f32x4 acc[4][4];
  #pragma unroll
  for (int i = 0; i < 4; ++i)
    #pragma unroll
    for (int j = 0; j < 4; ++j) { acc[i][j][0]=0.f; acc[i][j][1]=0.f; acc[i][j][2]=0.f; acc[i][j][3]=0.f; }

  for (int k0 = 0; k0 < K; k0 += 64) {
    #pragma unroll
    for (int p = 0; p < 4; ++p) {
      int c = p * 256 + tid;                    // 16B chunk index, linear LDS fill
      int row = c >> 3, colE = (c & 7) * 8;     // row, bf16-element col
      GLOAD_LDS(A + (size_t)(m0 + row) * K + k0 + colE, (char*)As + c * 16);
      GLOAD_LDS(B + (size_t)(n0 + row) * K + k0 + colE, (char*)Bs + c * 16);
    }
    __syncthreads();                            // vmcnt(0) drain of load_lds
    #pragma unroll
    for (int ks = 0; ks < 2; ++ks) {
      bf16x8 af[4], bfv[4];
      #pragma unroll
      for (int i = 0; i < 4; ++i) {
        af[i]  = *(const bf16x8*)((const char*)As + (wm + i * 16 + lrow) * 128 + ks * 64 + kbyte);
        bfv[i] = *(const bf16x8*)((const char*)Bs + (wn + i * 16 + lrow) * 128 + ks * 64 + kbyte);
      }
      #pragma unroll
      for (int i = 0; i < 4; ++i)
        #pragma unroll
        for (int j = 0; j < 4; ++j)
          acc[i][j] = __builtin_amdgcn_mfma_f32_16x16x32_bf16(af[i], bfv[j], acc[i][j], 0, 0, 0);
    }
    __syncthreads();
  }
  const int col = lane & 15;
  const int rbase = (lane >> 4) * 4;
  #pragma unroll
  for (int i = 0; i < 4; ++i)
    #pragma unroll
    for (int j = 0; j < 4; ++j) {
      int nn = n0 + wn + j * 16 + col;
      float bv = bias[nn];
      #pragma unroll
      for (int rr = 0; rr < 4; ++rr) {
        int mm = m0 + wm + i * 16 + rbase + rr;
        D[(size_t)mm * N + nn] = acc[i][j][rr] + bv;
      }
    }
}

// ---------------- persistent MFMA LSTM, two-phase batch pipeline ----------------
// 32 WGs x 4 waves. Wave W owns gate rows {g*512 + W*4+cl}; B-frags (weights)
// in VGPRs, SHARED by both phases. Batches split: phase A = 0-7 (lanegroups
// 0,1), phase B = 8-15 (lanegroups 2,3); separate counters cntA/cntB. Each
// phase's store-drain + signal propagation hides under the other phase's
// compute. L2-staleness rule: phase A must never touch slab-s rows 8-15
// (would cache torn lines) -> its nl>=8 lanes load duplicate rows (nl&7);
// phase B first-touches rows 8-15 after its poll.
__global__ __launch_bounds__(256) void k_lstm2(
    const float* __restrict__ xp, const float* __restrict__ Whh,
    __bf16* __restrict__ hs_full, int* __restrict__ cntA, int* __restrict__ cntB) {
  const int tid  = threadIdx.x;
  const int lane = tid & 63;
  const int wv   = tid >> 6;               // 0..3
  const int W    = blockIdx.x * 4 + wv;    // 0..127
  const int c0   = W * 4;                  // first cell owned by this wave
  const int nl   = lane & 15;              // MFMA col (n_local) / A row (batch)
  const int g    = nl >> 2, cl = nl & 3;
  const int Grow = g * 512 + c0 + cl;      // gate row in [0,2048)
  const int kb   = (lane >> 4) * 8;        // per-lane K offset
  const int B0   = (lane >> 4) * 4;        // batch base of acc regs
  const int grp  = B0 >> 3;                // 0: batches 0-7 (phase A), 1: 8-15 (B)

  // ---- B-frags: W_hh[Grow][k], fp32 -> bf16, 64 VGPRs, loaded once ----
  bf16x8 bfrag[16];
  #pragma unroll
  for (int kk = 0; kk < 16; ++kk) {
    const float4* src = (const float4*)(Whh + (size_t)Grow * 512 + kk * 32 + kb);
    float4 w0 = src[0], w1 = src[1];
    bf16x8 t = { (__bf16)w0.x, (__bf16)w0.y, (__bf16)w0.z, (__bf16)w0.w,
                 (__bf16)w1.x, (__bf16)w1.y, (__bf16)w1.z, (__bf16)w1.w };
    bfrag[kk] = t;
  }

  float c_reg[4] = {0.f, 0.f, 0.f, 0.f};
  f32x4 xq;                                // xp[s][B0+r][Grow] (per-lane batch)
  #pragma unroll
  for (int r = 0; r < 4; ++r) xq[r] = xp[(size_t)(B0 + r) * G4 + Grow];

  const int lbase = (lane & 48) | (lane & 3);
  const int wlane = ((lane & 12) == 0);    // 4 writer lanes per lanegroup

  for (int s = 0; s < S_LEN; ++s) {
    const __bf16* slab = hs_full + (size_t)s * 8192;
    __bf16* dstbase = hs_full + (size_t)(s + 1) * 8192 + (size_t)B0 * 512 + c0 + (lane & 3);

    #pragma unroll
    for (int P = 0; P < 2; ++P) {
      // ---- poll this phase's counter (skip s==0: target 0) ----
      if (s > 0 && tid == 0) {
        const int* cc = P ? cntB : cntA;
        while (load_cnt_sc(cc) < NWG_LSTM * s) {}
      }
      __syncthreads();                     // release: phase data now visible

      // A-frags: phase A reads rows 0-7 only (dup for nl>=8); phase B all rows
      const int arow = P ? nl : (nl & 7);
      const __bf16* hrow = slab + arow * 512 + kb;
      bf16x8 afrag[16];
      #pragma unroll
      for (int kk = 0; kk < 16; ++kk)
        afrag[kk] = *(const bf16x8*)(hrow + kk * 32);

      f32x4 acc0 = xq;                     // C-in = input projection (incl. biases)
      f32x4 acc1 = {0.f, 0.f, 0.f, 0.f};
      #pragma unroll
      for (int kk = 0; kk < 16; kk += 2) {
        acc0 = __builtin_amdgcn_mfma_f32_16x16x32_bf16(afrag[kk],     bfrag[kk],     acc0, 0, 0, 0);
        acc1 = __builtin_amdgcn_mfma_f32_16x16x32_bf16(afrag[kk + 1], bfrag[kk + 1], acc1, 0, 0, 0);
      }

      // prefetch next step's xp during phase B only (phase B still needs xq_s)
      if (P == 1 && s + 1 < S_LEN) {
        const float* nx = xp + ((size_t)(s + 1) * BATCH + B0) * G4 + Grow;
        #pragma unroll
        for (int r = 0; r < 4; ++r) xq[r] = nx[(size_t)r * G4];
      }

      f32x4 gates;
      #pragma unroll
      for (int r = 0; r < 4; ++r) gates[r] = acc0[r] + acc1[r];

      const int valid = (grp == P);
      #pragma unroll
      for (int r = 0; r < 4; ++r) {
        float ig = __shfl(gates[r], lbase + 0);
        float fg = __shfl(gates[r], lbase + 4);
        float gg = __shfl(gates[r], lbase + 8);
        float og = __shfl(gates[r], lbase + 12);
        float si = 1.f / (1.f + __expf(-ig));
        float sf = 1.f / (1.f + __expf(-fg));
        float so = 1.f / (1.f + __expf(-og));
        float ag = fabsf(gg), eg = __expf(-2.f * ag);
        float tg = __builtin_copysignf((1.f - eg) / (1.f + eg), gg);
        float c  = sf * c_reg[r] + si * tg;
        if (valid) c_reg[r] = c;
        float ac = fabsf(c), ec = __expf(-2.f * ac);
        float tc = __builtin_copysignf((1.f - ec) / (1.f + ec), c);
        float h  = so * tc;
        if (valid && wlane)                // this phase's 8 writer lanes
          store_short_sc(dstbase + (size_t)r * 512, (__bf16)h);
      }

      __syncthreads();                     // all waves drain phase stores (vmcnt 0)
      if (tid == 0) {
        int* cc = P ? cntB : cntA;
        __hip_atomic_fetch_add(cc, 1, __ATOMIC_RELAXED, __HIP_MEMORY_SCOPE_AGENT);
      }
    }
  }
}

// ---------------- in-place log_softmax over V=32000 ----------------
__global__ __launch_bounds__(256) void k_logsm(float* __restrict__ out) {
  const int row = blockIdx.x;
  float* p = out + (size_t)row * VOCAB;
  const int tid = threadIdx.x;
  float m = -INFINITY, ssum = 0.f;
  for (int i = tid; i < VOCAB / 4; i += 256) {
    float4 v = ((const float4*)p)[i];
    float nm = fmaxf(fmaxf(m, v.x), fmaxf(fmaxf(v.y, v.z), v.w));
    if (nm > m) { ssum *= __expf(m - nm); m = nm; }
    ssum += __expf(v.x - m) + __expf(v.y - m) + __expf(v.z - m) + __expf(v.w - m);
  }
  #pragma unroll
  for (int off = 32; off > 0; off >>= 1) {
    float mo = __shfl_down(m, off);
    float so = __shfl_down(ssum, off);
    float nm = fmaxf(m, mo);
    ssum = ssum * __expf(m - nm) + so * __expf(mo - nm);
    m = nm;
  }
  __shared__ float sm[4], ss[4], lse_s;
  int wid = tid >> 6;
  if ((tid & 63) == 0) { sm[wid] = m; ss[wid] = ssum; }
  __syncthreads();
  if (tid == 0) {
    float M = sm[0], Ssum = ss[0];
    #pragma unroll
    for (int w = 1; w < 4; ++w) {
      float nm = fmaxf(M, sm[w]);
      Ssum = Ssum * __expf(M - nm) + ss[w] * __expf(sm[w] - nm);
      M = nm;
    }
    lse_s = M + logf(Ssum);
  }
  __syncthreads();
  const float lse = lse_s;
  for (int i = tid; i < VOCAB / 4; i += 256) {
    float4 v = ((const float4*)p)[i];
    v.x -= lse; v.y -= lse; v.z -= lse; v.w -= lse;
    ((float4*)p)[i] = v;
  }
}

extern "C" void kernel_launch(void* const* d_in, const int* in_sizes, int n_in,
                              void* d_out, int out_size, void* d_ws, size_t ws_size,
                              hipStream_t stream) {
  const int*   tok   = (const int*)d_in[0];
  // d_in[1] = input_lengths: unused by the reference
  const float* embed = (const float*)d_in[2];
  const float* W_ih  = (const float*)d_in[3];
  const float* W_hh  = (const float*)d_in[4];
  const float* b_ih  = (const float*)d_in[5];
  const float* b_hh  = (const float*)d_in[6];
  const float* W_lin = (const float*)d_in[7];
  const float* b_lin = (const float*)d_in[8];
  float* out = (float*)d_out;
  char*  ws  = (char*)d_ws;

  int*    cntA     = (int*)(ws + OFF_CNTA);
  int*    cntB     = (int*)(ws + OFF_CNTB);
  float*  bias_sum = (float*)(ws + OFF_BIAS);
  __bf16* xb       = (__bf16*)(ws + OFF_X);
  __bf16* wihb     = (__bf16*)(ws + OFF_WIH);
  __bf16* wlinb    = (__bf16*)(ws + OFF_WLIN);
  float*  xp       = (float*)(ws + OFF_XP);
  __bf16* hs_full  = (__bf16*)(ws + OFF_HS);

  // zero barrier counters + h_0 slab (required every replay; both small)
  hipMemsetAsync(ws + OFF_CNTA, 0, 4096, stream);
  hipMemsetAsync(ws + OFF_HS, 0, BATCH * HDIM * sizeof(__bf16), stream);

  k_gather_cast_x<<<2048, 256, 0, stream>>>(tok, embed, xb);
  k_cast<<<1024, 256, 0, stream>>>(W_ih, wihb, G4 * EDIM / 4);
  k_cast<<<2048, 256, 0, stream>>>(W_lin, wlinb, VOCAB * HDIM / 4);
  k_bias<<<8, 256, 0, stream>>>(b_ih, b_hh, bias_sum);

  k_gemm2<<<dim3(G4 / 128, M_ROWS / 128), 256, 0, stream>>>(xb, wihb, xp, bias_sum, M_ROWS, G4, EDIM);
  k_lstm2<<<NWG_LSTM, 256, 0, stream>>>(xp, W_hh, hs_full, cntA, cntB);
  k_gemm2<<<dim3(VOCAB / 128, M_ROWS / 128), 256, 0, stream>>>(hs_full + BATCH * HDIM, wlinb, out, b_lin, M_ROWS, VOCAB, HDIM);
  k_logsm<<<4096, 256, 0, stream>>>(out);
}

// Round 7
// 1635.439 us; speedup vs baseline: 1.5808x; 1.5808x over previous
//
#include <hip/hip_runtime.h>
#include <hip/hip_bf16.h>

typedef __bf16 bf16x8 __attribute__((ext_vector_type(8)));
typedef __bf16 bf16x4 __attribute__((ext_vector_type(4)));
typedef float  f32x4  __attribute__((ext_vector_type(4)));

#define S_LEN  256
#define BATCH  16
#define EDIM   512
#define HDIM   512
#define VOCAB  32000
#define G4     2048          // 4*H
#define M_ROWS 4096          // S*B
#define NWG_LSTM 32
#define NTILE_N  (VOCAB / 128)   // 250 consumer n-tiles
#define NTILE_M  (M_ROWS / 128)  // 32 consumer m-tiles

// ------- ws layout (bytes) -------
#define OFF_CNT   0                         // int step counter (atomic barrier)
#define OFF_MIR   256                       // int mirror of completed step (own line)
#define OFF_BIAS  4096                      // float[2048] = b_ih + b_hh
#define OFF_X     12288                     // bf16[4096*512] gathered embeddings
#define OFF_WIH   (OFF_X + 4194304)         // bf16[2048*512]
#define OFF_WLIN  (OFF_WIH + 2097152)       // bf16[32000*512]
#define OFF_XP    (OFF_WLIN + 32768000)     // float[4096*2048]
#define OFF_HS    (OFF_XP + 33554432)       // bf16[257*16*512]; slab 0 zeroed (h_0)
// total = 76,836,864 bytes

// ---- device-coherent (write-through to Infinity Cache) ops ----
__device__ __forceinline__ void store_short_sc(__bf16* p, __bf16 v) {
  unsigned short u = __builtin_bit_cast(unsigned short, v);
  asm volatile("global_store_short %0, %1, off sc0 sc1" :: "v"(p), "v"(u) : "memory");
}
__device__ __forceinline__ void store_int_sc(int* p, int v) {
  asm volatile("global_store_dword %0, %1, off sc0 sc1" :: "v"(p), "v"(v) : "memory");
}
__device__ __forceinline__ int load_cnt_sc(const int* p) {
  int r;
  asm volatile("global_load_dword %0, %1, off sc0 sc1\n\ts_waitcnt vmcnt(0)"
               : "=v"(r) : "v"(p) : "memory");
  return r;
}

#define GLOAD_LDS(gsrc, ldst)                                                  \
  __builtin_amdgcn_global_load_lds(                                            \
      (const __attribute__((address_space(1))) void*)(gsrc),                   \
      (__attribute__((address_space(3))) void*)(ldst), 16, 0, 0)

// ---------------- prep kernels ----------------
__global__ __launch_bounds__(256) void k_gather_cast_x(
    const int* __restrict__ tok, const float* __restrict__ embed, __bf16* __restrict__ xb) {
  int i = blockIdx.x * blockDim.x + threadIdx.x;          // over 4096*128 float4 chunks
  const int total = M_ROWS * (EDIM / 4);
  for (; i < total; i += gridDim.x * blockDim.x) {
    int m = i >> 7, c = i & 127;
    int t = tok[m];
    float4 v = ((const float4*)(embed + (size_t)t * EDIM))[c];
    bf16x4 o = { (__bf16)v.x, (__bf16)v.y, (__bf16)v.z, (__bf16)v.w };
    ((bf16x4*)(xb + (size_t)m * EDIM))[c] = o;
  }
}

__global__ __launch_bounds__(256) void k_cast(
    const float* __restrict__ src, __bf16* __restrict__ dst, int n4) {
  int i = blockIdx.x * blockDim.x + threadIdx.x;
  for (; i < n4; i += gridDim.x * blockDim.x) {
    float4 v = ((const float4*)src)[i];
    bf16x4 o = { (__bf16)v.x, (__bf16)v.y, (__bf16)v.z, (__bf16)v.w };
    ((bf16x4*)dst)[i] = o;
  }
}

__global__ __launch_bounds__(256) void k_bias(
    const float* __restrict__ b_ih, const float* __restrict__ b_hh, float* __restrict__ bb) {
  int i = blockIdx.x * blockDim.x + threadIdx.x;
  if (i < G4) bb[i] = b_ih[i] + b_hh[i];
}

// ------- shared 128x128 MFMA GEMM tile body: D = A[M,K]*B[N,K]^T + bias -------
__device__ __forceinline__ void gemm_tile_body(
    const __bf16* __restrict__ A, const __bf16* __restrict__ B,
    float* __restrict__ D, const float* __restrict__ bias,
    int N, int K, int m0, int n0, __bf16* As, __bf16* Bs) {
  const int tid  = threadIdx.x;
  const int wave = tid >> 6, lane = tid & 63;
  const int wm   = (wave >> 1) * 64, wn = (wave & 1) * 64;
  const int lrow = lane & 15;
  const int kbyte = (lane >> 4) * 16;           // byte offset within 128B LDS row
  f32x4 acc[4][4];
  #pragma unroll
  for (int i = 0; i < 4; ++i)
    #pragma unroll
    for (int j = 0; j < 4; ++j) { acc[i][j][0]=0.f; acc[i][j][1]=0.f; acc[i][j][2]=0.f; acc[i][j][3]=0.f; }

  for (int k0 = 0; k0 < K; k0 += 64) {
    #pragma unroll
    for (int p = 0; p < 4; ++p) {
      int c = p * 256 + tid;                    // 16B chunk index, linear LDS fill
      int row = c >> 3, colE = (c & 7) * 8;     // row, bf16-element col
      GLOAD_LDS(A + (size_t)(m0 + row) * K + k0 + colE, (char*)As + c * 16);
      GLOAD_LDS(B + (size_t)(n0 + row) * K + k0 + colE, (char*)Bs + c * 16);
    }
    __syncthreads();                            // vmcnt(0) drain of load_lds
    #pragma unroll
    for (int ks = 0; ks < 2; ++ks) {
      bf16x8 af[4], bfv[4];
      #pragma unroll
      for (int i = 0; i < 4; ++i) {
        af[i]  = *(const bf16x8*)((const char*)As + (wm + i * 16 + lrow) * 128 + ks * 64 + kbyte);
        bfv[i] = *(const bf16x8*)((const char*)Bs + (wn + i * 16 + lrow) * 128 + ks * 64 + kbyte);
      }
      #pragma unroll
      for (int i = 0; i < 4; ++i)
        #pragma unroll
        for (int j = 0; j < 4; ++j)
          acc[i][j] = __builtin_amdgcn_mfma_f32_16x16x32_bf16(af[i], bfv[j], acc[i][j], 0, 0, 0);
    }
    __syncthreads();
  }
  const int col = lane & 15;
  const int rbase = (lane >> 4) * 4;
  #pragma unroll
  for (int i = 0; i < 4; ++i)
    #pragma unroll
    for (int j = 0; j < 4; ++j) {
      int nn = n0 + wn + j * 16 + col;
      float bv = bias[nn];
      #pragma unroll
      for (int rr = 0; rr < 4; ++rr) {
        int mm = m0 + wm + i * 16 + rbase + rr;
        D[(size_t)mm * N + nn] = acc[i][j][rr] + bv;
      }
    }
}

// standalone GEMM (xp projection)
__global__ __launch_bounds__(256) void k_gemm2(
    const __bf16* __restrict__ A, const __bf16* __restrict__ B,
    float* __restrict__ D, const float* __restrict__ bias, int N, int K) {
  __shared__ __align__(16) __bf16 As[128 * 64];
  __shared__ __align__(16) __bf16 Bs[128 * 64];
  gemm_tile_body(A, B, D, bias, N, K, blockIdx.y * 128, blockIdx.x * 128, As, Bs);
}

// ---------------- fused persistent LSTM + polling logits GEMM ----------------
// Blocks [0,32): R5 persistent MFMA LSTM (unchanged structure, setprio 1).
//   Producer WG 0 additionally mirrors the completed-step count to a separate
//   cacheline (MIR) so 8000 consumers don't hammer the atomic counter line.
// Blocks [32, 32+8000): logits GEMM tiles. Tile t: mt=t/250 needs steps
//   < 8*(mt+1); poll mirror (sc-coherent, s_sleep-throttled), then normal
//   GEMM. Every hs line is first-touched on any XCD only after its step is
//   final (producers read slab s post-barrier, consumers post-poll), so
//   normal cached loads are safe. Producers never wait on consumers ->
//   dispatch-order residency guarantees no deadlock.
__global__ __launch_bounds__(256) void k_lstm_fused(
    const float* __restrict__ xp, const float* __restrict__ Whh,
    __bf16* __restrict__ hs_full, int* __restrict__ cnt, int* __restrict__ mir,
    const __bf16* __restrict__ wlinb, float* __restrict__ out,
    const float* __restrict__ b_lin) {
  __shared__ __align__(16) __bf16 As[128 * 64];
  __shared__ __align__(16) __bf16 Bs[128 * 64];
  const int tid = threadIdx.x;

  if (blockIdx.x >= NWG_LSTM) {
    // ---------------- consumer: one 128x128 logits tile ----------------
    const int t  = blockIdx.x - NWG_LSTM;
    const int mt = t / NTILE_N, nt = t % NTILE_N;
    if (tid == 0) {
      const int need = 8 * (mt + 1);           // steps 8*mt .. 8*mt+7 complete
      while (load_cnt_sc(mir) < need) __builtin_amdgcn_s_sleep(16);
    }
    __syncthreads();
    gemm_tile_body(hs_full + BATCH * HDIM, wlinb, out, b_lin,
                   VOCAB, HDIM, mt * 128, nt * 128, As, Bs);
    return;
  }

  // ---------------- producer: persistent LSTM (R5 structure) ----------------
  __builtin_amdgcn_s_setprio(1);
  const int lane = tid & 63;
  const int wv   = tid >> 6;               // 0..3
  const int W    = blockIdx.x * 4 + wv;    // 0..127
  const int c0   = W * 4;                  // first cell owned by this wave
  const int nl   = lane & 15;              // MFMA col (n_local) / A row (batch)
  const int g    = nl >> 2, cl = nl & 3;
  const int Grow = g * 512 + c0 + cl;      // gate row in [0,2048)
  const int kb   = (lane >> 4) * 8;        // per-lane K offset
  const int B0   = (lane >> 4) * 4;        // batch base of acc regs

  // ---- B-frags: W_hh[Grow][k], fp32 -> bf16, 64 VGPRs, loaded once ----
  bf16x8 bfrag[16];
  #pragma unroll
  for (int kk = 0; kk < 16; ++kk) {
    const float4* src = (const float4*)(Whh + (size_t)Grow * 512 + kk * 32 + kb);
    float4 w0 = src[0], w1 = src[1];
    bf16x8 tt = { (__bf16)w0.x, (__bf16)w0.y, (__bf16)w0.z, (__bf16)w0.w,
                  (__bf16)w1.x, (__bf16)w1.y, (__bf16)w1.z, (__bf16)w1.w };
    bfrag[kk] = tt;
  }

  float c_reg[4] = {0.f, 0.f, 0.f, 0.f};
  f32x4 xq;                                // xp[s][B0+r][Grow], prefetched
  #pragma unroll
  for (int r = 0; r < 4; ++r) xq[r] = xp[(size_t)(B0 + r) * G4 + Grow];

  for (int s = 0; s < S_LEN; ++s) {
    // A-frags: h_s[batch=nl][k], 16B loads (first-touch; L3-resident slab)
    const __bf16* hrow = hs_full + (size_t)s * 8192 + nl * 512 + kb;
    bf16x8 afrag[16];
    #pragma unroll
    for (int kk = 0; kk < 16; ++kk)
      afrag[kk] = *(const bf16x8*)(hrow + kk * 32);

    f32x4 acc0 = xq;                       // C-in = input projection (incl. biases)
    f32x4 acc1 = {0.f, 0.f, 0.f, 0.f};
    #pragma unroll
    for (int kk = 0; kk < 16; kk += 2) {
      acc0 = __builtin_amdgcn_mfma_f32_16x16x32_bf16(afrag[kk],     bfrag[kk],     acc0, 0, 0, 0);
      acc1 = __builtin_amdgcn_mfma_f32_16x16x32_bf16(afrag[kk + 1], bfrag[kk + 1], acc1, 0, 0, 0);
    }

    // prefetch next step's xp while MFMA drains
    if (s + 1 < S_LEN) {
      const float* nx = xp + ((size_t)(s + 1) * BATCH + B0) * G4 + Grow;
      #pragma unroll
      for (int r = 0; r < 4; ++r) xq[r] = nx[(size_t)r * G4];
    }

    f32x4 gates;
    #pragma unroll
    for (int r = 0; r < 4; ++r) gates[r] = acc0[r] + acc1[r];

    // redistribute: this lane takes i,f,g,o of cell c0+(lane&3), batches B0..B0+3
    const int lbase = (lane & 48) | (lane & 3);
    __bf16* dstbase = hs_full + (size_t)(s + 1) * 8192 + (size_t)B0 * 512 + c0 + (lane & 3);
    #pragma unroll
    for (int r = 0; r < 4; ++r) {
      float ig = __shfl(gates[r], lbase + 0);
      float fg = __shfl(gates[r], lbase + 4);
      float gg = __shfl(gates[r], lbase + 8);
      float og = __shfl(gates[r], lbase + 12);
      float si = 1.f / (1.f + __expf(-ig));
      float sf = 1.f / (1.f + __expf(-fg));
      float so = 1.f / (1.f + __expf(-og));
      float ag = fabsf(gg), eg = __expf(-2.f * ag);
      float tg = __builtin_copysignf((1.f - eg) / (1.f + eg), gg);
      float c  = sf * c_reg[r] + si * tg;
      c_reg[r] = c;
      float ac = fabsf(c), ec = __expf(-2.f * ac);
      float tc = __builtin_copysignf((1.f - ec) / (1.f + ec), c);
      float h  = so * tc;
      if ((lane & 12) == 0)                // 16 writer lanes: store as soon as computed
        store_short_sc(dstbase + (size_t)r * 512, (__bf16)h);
    }

    __syncthreads();                       // every wave drains its sc1 stores (vmcnt 0)
    if (tid == 0) {
      __hip_atomic_fetch_add(cnt, 1, __ATOMIC_RELAXED, __HIP_MEMORY_SCOPE_AGENT);
      const int target = NWG_LSTM * (s + 1);
      while (load_cnt_sc(cnt) < target) {}
      if (blockIdx.x == 0)                 // fire-and-forget mirror for consumers
        store_int_sc(mir, s + 1);
    }
    __syncthreads();
  }
}

// ---------------- in-place log_softmax over V=32000 ----------------
__global__ __launch_bounds__(256) void k_logsm(float* __restrict__ out) {
  const int row = blockIdx.x;
  float* p = out + (size_t)row * VOCAB;
  const int tid = threadIdx.x;
  float m = -INFINITY, ssum = 0.f;
  for (int i = tid; i < VOCAB / 4; i += 256) {
    float4 v = ((const float4*)p)[i];
    float nm = fmaxf(fmaxf(m, v.x), fmaxf(fmaxf(v.y, v.z), v.w));
    if (nm > m) { ssum *= __expf(m - nm); m = nm; }
    ssum += __expf(v.x - m) + __expf(v.y - m) + __expf(v.z - m) + __expf(v.w - m);
  }
  #pragma unroll
  for (int off = 32; off > 0; off >>= 1) {
    float mo = __shfl_down(m, off);
    float so = __shfl_down(ssum, off);
    float nm = fmaxf(m, mo);
    ssum = ssum * __expf(m - nm) + so * __expf(mo - nm);
    m = nm;
  }
  __shared__ float sm[4], ss[4], lse_s;
  int wid = tid >> 6;
  if ((tid & 63) == 0) { sm[wid] = m; ss[wid] = ssum; }
  __syncthreads();
  if (tid == 0) {
    float M = sm[0], Ssum = ss[0];
    #pragma unroll
    for (int w = 1; w < 4; ++w) {
      float nm = fmaxf(M, sm[w]);
      Ssum = Ssum * __expf(M - nm) + ss[w] * __expf(sm[w] - nm);
      M = nm;
    }
    lse_s = M + logf(Ssum);
  }
  __syncthreads();
  const float lse = lse_s;
  for (int i = tid; i < VOCAB / 4; i += 256) {
    float4 v = ((const float4*)p)[i];
    v.x -= lse; v.y -= lse; v.z -= lse; v.w -= lse;
    ((float4*)p)[i] = v;
  }
}

extern "C" void kernel_launch(void* const* d_in, const int* in_sizes, int n_in,
                              void* d_out, int out_size, void* d_ws, size_t ws_size,
                              hipStream_t stream) {
  const int*   tok   = (const int*)d_in[0];
  // d_in[1] = input_lengths: unused by the reference
  const float* embed = (const float*)d_in[2];
  const float* W_ih  = (const float*)d_in[3];
  const float* W_hh  = (const float*)d_in[4];
  const float* b_ih  = (const float*)d_in[5];
  const float* b_hh  = (const float*)d_in[6];
  const float* W_lin = (const float*)d_in[7];
  const float* b_lin = (const float*)d_in[8];
  float* out = (float*)d_out;
  char*  ws  = (char*)d_ws;

  int*    cnt      = (int*)(ws + OFF_CNT);
  int*    mir      = (int*)(ws + OFF_MIR);
  float*  bias_sum = (float*)(ws + OFF_BIAS);
  __bf16* xb       = (__bf16*)(ws + OFF_X);
  __bf16* wihb     = (__bf16*)(ws + OFF_WIH);
  __bf16* wlinb    = (__bf16*)(ws + OFF_WLIN);
  float*  xp       = (float*)(ws + OFF_XP);
  __bf16* hs_full  = (__bf16*)(ws + OFF_HS);

  // zero barrier counter + mirror + h_0 slab (required every replay)
  hipMemsetAsync(ws + OFF_CNT, 0, 4096, stream);
  hipMemsetAsync(ws + OFF_HS, 0, BATCH * HDIM * sizeof(__bf16), stream);

  k_gather_cast_x<<<2048, 256, 0, stream>>>(tok, embed, xb);
  k_cast<<<1024, 256, 0, stream>>>(W_ih, wihb, G4 * EDIM / 4);
  k_cast<<<2048, 256, 0, stream>>>(W_lin, wlinb, VOCAB * HDIM / 4);
  k_bias<<<8, 256, 0, stream>>>(b_ih, b_hh, bias_sum);

  k_gemm2<<<dim3(G4 / 128, M_ROWS / 128), 256, 0, stream>>>(xb, wihb, xp, bias_sum, G4, EDIM);
  k_lstm_fused<<<NWG_LSTM + NTILE_M * NTILE_N, 256, 0, stream>>>(
      xp, W_hh, hs_full, cnt, mir, wlinb, out, b_lin);
  k_logsm<<<4096, 256, 0, stream>>>(out);
}